// Round 3
// baseline (335.799 us; speedup 1.0000x reference)
//
#include <hip/hip_runtime.h>

typedef float f32x4 __attribute__((ext_vector_type(4)));

// Single fused kernel. One wave == 4 consecutive output rows for ONE q-quadrant.
// wid = (q, bc, ygrp) with q SLOWEST: all concurrently-resident blocks write into
// one q-slice (~67 MB window) instead of scattering over the full 268 MB output.
// Image is re-read once per q-phase (4x) but stays L3-resident (64 MB < 256 MB L3).
// grid: 4096 blocks x 256 threads = 16384 waves.
__global__ __launch_bounds__(256) void qwt_main_kernel(const float* __restrict__ img,
                                                       const float* __restrict__ gl,
                                                       const float* __restrict__ gh,
                                                       const float* __restrict__ fl,
                                                       const float* __restrict__ fh,
                                                       float* __restrict__ out) {
    const float w0 = -0.09375f, w1 = 0.59375f;  // CUBIC_W = {w0, w1, w1, w0}

    int t    = blockIdx.x * 256 + threadIdx.x;
    int lane = t & 63;
    int wid  = t >> 6;          // 0..16383
    int q    = wid >> 12;       // 0..3, slowest -> phase-clustered writes
    int bc   = (wid >> 6) & 63; // b*16 + c
    int ygrp = wid & 63;
    int y0   = ygrp << 2;       // first output row
    int x0   = lane << 2;       // 4 output px per lane per row

    // Filter sums computed per-wave (lanes 0-3, 16 scalar loads each -> L1 hits),
    // broadcast via shuffle. Removes the separate 1-block pre-kernel launch.
    float s = 0.f;
    if (lane < 4) {
        const float* p = (lane == 0) ? gl : (lane == 1) ? gh : (lane == 2) ? fl : fh;
        #pragma unroll
        for (int i = 0; i < 16; i++) s += p[i];
    }
    float sg  = __shfl(s, 0);
    float sh  = __shfl(s, 1);
    float sfl = __shfl(s, 2);
    float sfh = __shfl(s, 3);

    const float* src = img + (size_t)bc * (512 * 512);

    // Horizontal bicubic over the 10 unique source rows: 2*y0-1 .. 2*y0+8 (clamped).
    float h[10][4];
    #pragma unroll
    for (int k = 0; k < 10; k++) {
        int sr = 2 * y0 - 1 + k;                     // wave-uniform
        sr = sr < 0 ? 0 : (sr > 511 ? 511 : sr);
        const f32x4* rp4 = (const f32x4*)(src + (size_t)sr * 512);
        f32x4 v0 = rp4[2 * lane];
        f32x4 v1 = rp4[2 * lane + 1];
        float left  = __shfl_up(v1.w, 1);            // col 8*lane - 1
        float right = __shfl_down(v0.x, 1);          // col 8*lane + 8
        if (lane == 0)  left  = v0.x;                // clamp col -1 -> 0
        if (lane == 63) right = v1.w;                // clamp col 512 -> 511

        h[k][0] = w0 * left + w1 * v0.x + w1 * v0.y + w0 * v0.z;
        h[k][1] = w0 * v0.y + w1 * v0.z + w1 * v0.w + w0 * v1.x;
        h[k][2] = w0 * v0.w + w1 * v1.x + w1 * v1.y + w0 * v1.z;
        h[k][3] = w0 * v1.y + w1 * v1.z + w1 * v1.w + w0 * right;
    }

    // Vertical pass: acc[r][i] = downsampled value at (y0+r, x0+i).
    f32x4 acc[4];
    #pragma unroll
    for (int r = 0; r < 4; r++) {
        #pragma unroll
        for (int i = 0; i < 4; i++) {
            acc[r][i] = w0 * h[2 * r][i] + w1 * h[2 * r + 1][i]
                      + w1 * h[2 * r + 2][i] + w0 * h[2 * r + 3][i];
        }
    }

    // This wave's q-quadrant scales.
    float f1g = (q & 1) ? sfl : sg;
    float f1h = (q & 1) ? sfh : sh;
    float f2g = (q & 2) ? sfl : sg;
    float f2h = (q & 2) ? sfh : sh;
    float sLL = f1g * f2g;
    float s0  = f1g * f2h;
    float s1  = f1h * f2g;
    float s2  = f1h * f2h;

    int b   = bc >> 4;
    int cc_ = bc & 15;
    size_t rowoff = ((size_t)y0 << 8) + (size_t)x0;
    const size_t P  = 65536;       // 256*256
    const size_t HB = 16777216;    // LL element count

    size_t chan = (size_t)(b * 64 + q * 16 + cc_);
    float* llp = out + chan * P + rowoff;
    float* hp  = out + HB + chan * 3 * P + rowoff;

    #pragma unroll
    for (int r = 0; r < 4; r++) {
        f32x4 v = {acc[r][0] * sLL, acc[r][1] * sLL, acc[r][2] * sLL, acc[r][3] * sLL};
        __builtin_nontemporal_store(v, (f32x4*)(llp + r * 256));
    }
    #pragma unroll
    for (int r = 0; r < 4; r++) {
        f32x4 v = {acc[r][0] * s0, acc[r][1] * s0, acc[r][2] * s0, acc[r][3] * s0};
        __builtin_nontemporal_store(v, (f32x4*)(hp + r * 256));
    }
    #pragma unroll
    for (int r = 0; r < 4; r++) {
        f32x4 v = {acc[r][0] * s1, acc[r][1] * s1, acc[r][2] * s1, acc[r][3] * s1};
        __builtin_nontemporal_store(v, (f32x4*)(hp + P + r * 256));
    }
    #pragma unroll
    for (int r = 0; r < 4; r++) {
        f32x4 v = {acc[r][0] * s2, acc[r][1] * s2, acc[r][2] * s2, acc[r][3] * s2};
        __builtin_nontemporal_store(v, (f32x4*)(hp + 2 * P + r * 256));
    }
}

extern "C" void kernel_launch(void* const* d_in, const int* in_sizes, int n_in,
                              void* d_out, int out_size, void* d_ws, size_t ws_size,
                              hipStream_t stream) {
    const float* img = (const float*)d_in[0];
    const float* gl  = (const float*)d_in[1];
    const float* gh  = (const float*)d_in[2];
    const float* fl  = (const float*)d_in[3];
    const float* fh  = (const float*)d_in[4];
    float* out = (float*)d_out;

    // 16384 waves: q (write-phase) slowest, then bc, then 4-row groups.
    qwt_main_kernel<<<4096, 256, 0, stream>>>(img, gl, gh, fl, fh, out);
}

// Round 4
// 313.985 us; speedup vs baseline: 1.0695x; 1.0695x over previous
//
#include <hip/hip_runtime.h>

typedef float f32x4 __attribute__((ext_vector_type(4)));

// One wave (64 lanes) == one output row (256 px, 4 px/lane).
// grid: 4096 blocks x 256 threads = 16384 waves = 4*16*256 rows.
// Best-measured structure (R1, 318.3 us total): coalesced float4 reads with
// shuffle halo, nontemporal float4 stores, filter sums fused in-wave.
__global__ __launch_bounds__(256) void qwt_main_kernel(const float* __restrict__ img,
                                                       const float* __restrict__ gl,
                                                       const float* __restrict__ gh,
                                                       const float* __restrict__ fl,
                                                       const float* __restrict__ fh,
                                                       float* __restrict__ out) {
    const float w0 = -0.09375f, w1 = 0.59375f;  // CUBIC_W = {w0, w1, w1, w0}

    int t    = blockIdx.x * 256 + threadIdx.x;
    int lane = t & 63;
    int row  = t >> 6;        // 0..16383 flat (b,c,y)
    int y    = row & 255;
    int bc   = row >> 8;      // 0..63 = b*16 + c
    int x0   = lane << 2;     // 4 output px per lane

    // Filter sums computed per-wave (lanes 0-3 each sum one 16-tap filter,
    // L1-broadcast loads), then shuffle-broadcast. No separate launch.
    float s = 0.f;
    if (lane < 4) {
        const float* p = (lane == 0) ? gl : (lane == 1) ? gh : (lane == 2) ? fl : fh;
        #pragma unroll
        for (int i = 0; i < 16; i++) s += p[i];
    }
    float sg  = __shfl(s, 0);
    float sh  = __shfl(s, 1);
    float sfl = __shfl(s, 2);
    float sfh = __shfl(s, 3);

    const float* src = img + (size_t)bc * (512 * 512);

    float acc0 = 0.f, acc1 = 0.f, acc2 = 0.f, acc3 = 0.f;
    #pragma unroll
    for (int j = 0; j < 4; j++) {
        int ry = 2 * y - 1 + j;               // wave-uniform
        ry = ry < 0 ? 0 : (ry > 511 ? 511 : ry);
        const f32x4* rp4 = (const f32x4*)(src + (size_t)ry * 512);
        // lane covers source cols 8*lane .. 8*lane+7, 16B-aligned
        f32x4 v0 = rp4[2 * lane];
        f32x4 v1 = rp4[2 * lane + 1];
        // halo columns via cross-lane shuffle; border clamp at lane 0 / 63
        float left  = __shfl_up(v1.w, 1);     // col 8*lane - 1
        float right = __shfl_down(v0.x, 1);   // col 8*lane + 8
        if (lane == 0)  left  = v0.x;         // clamp col -1 -> 0
        if (lane == 63) right = v1.w;         // clamp col 512 -> 511

        float h0 = w0 * left + w1 * v0.x + w1 * v0.y + w0 * v0.z;
        float h1 = w0 * v0.y + w1 * v0.z + w1 * v0.w + w0 * v1.x;
        float h2 = w0 * v0.w + w1 * v1.x + w1 * v1.y + w0 * v1.z;
        float h3 = w0 * v1.y + w1 * v1.z + w1 * v1.w + w0 * right;

        float wj = (j == 0 || j == 3) ? w0 : w1;
        acc0 += wj * h0; acc1 += wj * h1; acc2 += wj * h2; acc3 += wj * h3;
    }

    int b   = bc >> 4;          // batch 0..3
    int cc_ = bc & 15;          // channel 0..15
    size_t rowoff = ((size_t)y << 8) + (size_t)x0;   // y*256 + x0
    const size_t P  = 65536;                         // 256*256
    const size_t HB = 16777216;                      // LL element count

    // chan = b*64 + q*16 + cc_; per-q step is 16*P (LL) / 48*P (H).
    float* llp = out + ((size_t)(b * 64 + cc_)) * P + rowoff;
    float* hp  = out + HB + ((size_t)(b * 64 + cc_)) * 3 * P + rowoff;

    #pragma unroll
    for (int q = 0; q < 4; q++) {
        float f1g = (q & 1) ? sfl : sg;
        float f1h = (q & 1) ? sfh : sh;
        float f2g = (q & 2) ? sfl : sg;
        float f2h = (q & 2) ? sfh : sh;

        {
            float sc = f1g * f2g;
            f32x4 v = {acc0 * sc, acc1 * sc, acc2 * sc, acc3 * sc};
            __builtin_nontemporal_store(v, (f32x4*)llp);
        }
        {
            float sc = f1g * f2h;
            f32x4 v = {acc0 * sc, acc1 * sc, acc2 * sc, acc3 * sc};
            __builtin_nontemporal_store(v, (f32x4*)hp);
        }
        {
            float sc = f1h * f2g;
            f32x4 v = {acc0 * sc, acc1 * sc, acc2 * sc, acc3 * sc};
            __builtin_nontemporal_store(v, (f32x4*)(hp + P));
        }
        {
            float sc = f1h * f2h;
            f32x4 v = {acc0 * sc, acc1 * sc, acc2 * sc, acc3 * sc};
            __builtin_nontemporal_store(v, (f32x4*)(hp + 2 * P));
        }

        llp += 16 * P;
        hp  += 48 * P;
    }
}

extern "C" void kernel_launch(void* const* d_in, const int* in_sizes, int n_in,
                              void* d_out, int out_size, void* d_ws, size_t ws_size,
                              hipStream_t stream) {
    const float* img = (const float*)d_in[0];
    const float* gl  = (const float*)d_in[1];
    const float* gh  = (const float*)d_in[2];
    const float* fl  = (const float*)d_in[3];
    const float* fh  = (const float*)d_in[4];
    float* out = (float*)d_out;

    qwt_main_kernel<<<4096, 256, 0, stream>>>(img, gl, gh, fl, fh, out);
}